// Round 3
// baseline (420.472 us; speedup 1.0000x reference)
//
#include <hip/hip_runtime.h>
#include <stdint.h>

#define G   128
#define TT  96
#define NB  2
#define NC  4
#define CS  (TT * TT * TT)
#define NBK (48 * 48 * 48)   // Morton 2x2x2 blocks per batch

__device__ __forceinline__ uint16_t f2h(float f) {
    union { uint16_t u; _Float16 h; } v; v.h = (_Float16)f; return v.u;
}
__device__ __forceinline__ void unpack4(uint64_t v, float f[4]) {
    union { uint32_t u; _Float16 h[2]; } a, b;
    a.u = (uint32_t)v; b.u = (uint32_t)(v >> 32);
    f[0] = (float)a.h[0]; f[1] = (float)a.h[1];
    f[2] = (float)b.h[0]; f[3] = (float)b.h[1];
}

// Prepass: template [B,C,z,y,x] fp32 -> Morton-blocked channels-packed fp16.
// One thread per 2x2x2 block; each thread writes one full 64B line.
__global__ __launch_bounds__(256) void tmpl_repack_kernel(
        const float* __restrict__ tmpl, uint64_t* __restrict__ out) {
    int idx = blockIdx.x * 256 + threadIdx.x;
    if (idx >= NB * NBK) return;
    int b = idx / NBK;
    int s = idx - b * NBK;
    int bz = s / (48 * 48);
    int r  = s - bz * 48 * 48;
    int by = r / 48;
    int bx = r - by * 48;
    const float* base = tmpl + (size_t)b * NC * CS
                      + (((size_t)(bz << 1) * TT + (by << 1)) * TT + (bx << 1));
    uint64_t vox[8];
#pragma unroll
    for (int lz = 0; lz < 2; ++lz)
#pragma unroll
    for (int ly = 0; ly < 2; ++ly)
#pragma unroll
    for (int lx = 0; lx < 2; ++lx) {
        uint64_t p = 0;
#pragma unroll
        for (int c = 0; c < NC; ++c) {
            float f = base[(size_t)c * CS + (lz * TT + ly) * TT + lx];
            p |= (uint64_t)f2h(f) << (16 * c);
        }
        vox[(lz << 2) | (ly << 1) | lx] = p;
    }
    uint64_t* o = out + ((size_t)b * NBK + s) * 8;
#pragma unroll
    for (int k = 0; k < 8; ++k) o[k] = vox[k];
}

// One block = tile of 32(d) x 32(w) at fixed (b, h).
template <bool PACKED>
__global__ __launch_bounds__(256) void fused_sample_kernel(
        const float* __restrict__ grids,
        const float* __restrict__ deform,
        const float* __restrict__ corr,
        const uint64_t* __restrict__ tmpl_mx,  // Morton fp16, used when PACKED
        const float* __restrict__ tmpl_raw,    // fallback
        float* __restrict__ out2,
        float* __restrict__ defp) {
    __shared__ float lds_def[3][32][33];    // [c][i=w][j=d] (+1 pad)
    __shared__ float lds_field[3][32][33];  // [c][j=d][i=w] (+1 pad)

    int blk = blockIdx.x;
    int wt = blk & 3;
    int dt = (blk >> 2) & 3;
    int h  = (blk >> 4) & 127;
    int b  = blk >> 11;
    int w0 = wt << 5, d0 = dt << 5;
    int tid = threadIdx.x;

    // ---- stage 1: deformation[b,c,w,h,d] -> lds_def[c][i][j], 16B loads along d
    for (int idx = tid; idx < 768; idx += 256) {   // 3c * 32i * 8 quads
        int c   = idx >> 8;
        int rem = idx & 255;
        int i   = rem >> 3;
        int j4  = (rem & 7) << 2;
        size_t off = ((((size_t)b * 3 + c) * G + (w0 + i)) * G + h) * G + (d0 + j4);
        float4 v = *(const float4*)(deform + off);
        lds_def[c][i][j4 + 0] = v.x;
        lds_def[c][i][j4 + 1] = v.y;
        lds_def[c][i][j4 + 2] = v.z;
        lds_def[c][i][j4 + 3] = v.w;
    }
    __syncthreads();

    // ---- stage 2: grids ((w,c)-contig) + def -> tanh field in LDS; write defp
    for (int idx = tid; idx < 768; idx += 256) {   // 32 rows * 24 float4-chunks
        int j = idx / 24;
        int t = idx - j * 24;
        size_t off = (((((size_t)b * G + (d0 + j)) * G + h) * G + w0) * 3) + (size_t)t * 4;
        float gv[4], dv[4];
        *(float4*)gv = *(const float4*)(grids + off);
#pragma unroll
        for (int k = 0; k < 4; ++k) {
            int e = t * 4 + k;
            int i = e / 3;
            int c = e - 3 * i;
            float d = lds_def[c][i][j];
            lds_field[c][j][i] = tanhf(gv[k] + d);
            dv[k] = d;                               // exact pass-through
        }
        *(float4*)(defp + off) = *(float4*)dv;
    }
    __syncthreads();

    // ---- stage 3: trilinear gather + correction; out2 d-contig across threads
    const float SC = 0.5f * (TT - 1);
    for (int p = tid; p < 1024; p += 256) {
        int i = p >> 5;        // w offset
        int j = p & 31;        // d offset
        float ix = (lds_field[0][j][i] + 1.0f) * SC;
        float iy = (lds_field[1][j][i] + 1.0f) * SC;
        float iz = (lds_field[2][j][i] + 1.0f) * SC;
        float x0f = floorf(ix), y0f = floorf(iy), z0f = floorf(iz);
        float wx = ix - x0f, wy = iy - y0f, wz = iz - z0f;
        int x0 = min(max((int)x0f, 0), TT - 1);
        int y0 = min(max((int)y0f, 0), TT - 1);
        int z0 = min(max((int)z0f, 0), TT - 1);
        int x1 = min(x0 + 1, TT - 1);
        int y1 = min(y0 + 1, TT - 1);
        int z1 = min(z0 + 1, TT - 1);
        float mx = 1.0f - wx, my = 1.0f - wy, mz = 1.0f - wz;
        float w000 = mx * my * mz, w001 = wx * my * mz;
        float w010 = mx * wy * mz, w011 = wx * wy * mz;
        float w100 = mx * my * wz, w101 = wx * my * wz;
        float w110 = mx * wy * wz, w111 = wx * wy * wz;

        float r[4] = {0.f, 0.f, 0.f, 0.f};
        if (PACKED) {
            const uint64_t* tb = tmpl_mx + (size_t)b * CS;
            int bx0 = x0 >> 1, bx1 = x1 >> 1, lx0 = x0 & 1, lx1 = x1 & 1;
            int by0 = y0 >> 1, by1 = y1 >> 1, ly0 = (y0 & 1) << 1, ly1 = (y1 & 1) << 1;
            int bz0 = z0 >> 1, bz1 = z1 >> 1, lz0 = (z0 & 1) << 2, lz1 = (z1 & 1) << 2;
            int rz0y0 = (bz0 * 48 + by0) * 48, rz0y1 = (bz0 * 48 + by1) * 48;
            int rz1y0 = (bz1 * 48 + by0) * 48, rz1y1 = (bz1 * 48 + by1) * 48;
            uint64_t v000 = tb[(size_t)((rz0y0 + bx0) << 3) + (lz0 | ly0 | lx0)];
            uint64_t v001 = tb[(size_t)((rz0y0 + bx1) << 3) + (lz0 | ly0 | lx1)];
            uint64_t v010 = tb[(size_t)((rz0y1 + bx0) << 3) + (lz0 | ly1 | lx0)];
            uint64_t v011 = tb[(size_t)((rz0y1 + bx1) << 3) + (lz0 | ly1 | lx1)];
            uint64_t v100 = tb[(size_t)((rz1y0 + bx0) << 3) + (lz1 | ly0 | lx0)];
            uint64_t v101 = tb[(size_t)((rz1y0 + bx1) << 3) + (lz1 | ly0 | lx1)];
            uint64_t v110 = tb[(size_t)((rz1y1 + bx0) << 3) + (lz1 | ly1 | lx0)];
            uint64_t v111 = tb[(size_t)((rz1y1 + bx1) << 3) + (lz1 | ly1 | lx1)];
            float f[4];
            unpack4(v000, f);
#pragma unroll
            for (int c = 0; c < 4; ++c) r[c] += f[c] * w000;
            unpack4(v001, f);
#pragma unroll
            for (int c = 0; c < 4; ++c) r[c] += f[c] * w001;
            unpack4(v010, f);
#pragma unroll
            for (int c = 0; c < 4; ++c) r[c] += f[c] * w010;
            unpack4(v011, f);
#pragma unroll
            for (int c = 0; c < 4; ++c) r[c] += f[c] * w011;
            unpack4(v100, f);
#pragma unroll
            for (int c = 0; c < 4; ++c) r[c] += f[c] * w100;
            unpack4(v101, f);
#pragma unroll
            for (int c = 0; c < 4; ++c) r[c] += f[c] * w101;
            unpack4(v110, f);
#pragma unroll
            for (int c = 0; c < 4; ++c) r[c] += f[c] * w110;
            unpack4(v111, f);
#pragma unroll
            for (int c = 0; c < 4; ++c) r[c] += f[c] * w111;
        } else {
            size_t i000 = ((size_t)z0 * TT + y0) * TT + x0;
            size_t i001 = ((size_t)z0 * TT + y0) * TT + x1;
            size_t i010 = ((size_t)z0 * TT + y1) * TT + x0;
            size_t i011 = ((size_t)z0 * TT + y1) * TT + x1;
            size_t i100 = ((size_t)z1 * TT + y0) * TT + x0;
            size_t i101 = ((size_t)z1 * TT + y0) * TT + x1;
            size_t i110 = ((size_t)z1 * TT + y1) * TT + x0;
            size_t i111 = ((size_t)z1 * TT + y1) * TT + x1;
#pragma unroll
            for (int c = 0; c < NC; ++c) {
                const float* tb = tmpl_raw + ((size_t)b * NC + c) * CS;
                r[c] = tb[i000]*w000 + tb[i001]*w001 + tb[i010]*w010 + tb[i011]*w011
                     + tb[i100]*w100 + tb[i101]*w101 + tb[i110]*w110 + tb[i111]*w111;
            }
        }

        int w = w0 + i, d = d0 + j;
        size_t obase = ((((size_t)b * NC) * (size_t)G + w) * G + h) * G + d;
        const size_t cstride = (size_t)G * G * G;
#pragma unroll
        for (int c = 0; c < NC; ++c) {
            size_t oidx = obase + c * cstride;
            out2[oidx] = r[c] + corr[oidx];
        }
    }
}

extern "C" void kernel_launch(void* const* d_in, const int* in_sizes, int n_in,
                              void* d_out, int out_size, void* d_ws, size_t ws_size,
                              hipStream_t stream) {
    const float* grids  = (const float*)d_in[0];
    const float* deform = (const float*)d_in[1];
    const float* corr   = (const float*)d_in[2];
    const float* tmpl   = (const float*)d_in[3];
    float* out2 = (float*)d_out;
    float* defp = out2 + (size_t)NB * NC * G * G * G;   // outputs concatenated flat
    uint64_t* tmpl_mx = (uint64_t*)d_ws;

    const size_t ws_needed = (size_t)NB * CS * sizeof(uint64_t);  // 14.16 MB
    const bool packed = (ws_size >= ws_needed);

    if (packed) {
        int nthr = NB * NBK;
        tmpl_repack_kernel<<<(nthr + 255) / 256, 256, 0, stream>>>(tmpl, tmpl_mx);
    }

    int nblk = NB * G * 16;   // (b,h) * 4 w-tiles * 4 d-tiles = 4096 blocks
    if (packed) {
        fused_sample_kernel<true><<<nblk, 256, 0, stream>>>(
            grids, deform, corr, tmpl_mx, tmpl, out2, defp);
    } else {
        fused_sample_kernel<false><<<nblk, 256, 0, stream>>>(
            grids, deform, corr, tmpl_mx, tmpl, out2, defp);
    }
}